// Round 9
// baseline (184.931 us; speedup 1.0000x reference)
//
#include <hip/hip_runtime.h>

#define NG 12
#define SD 64
#define ED 768
#define NB 262144
#define TPB 192          // 3 waves; thread t owns output cols [4t, 4t+4)
#define G   4096         // grid size; ITERS grid-stride iterations per block
#define ITERS (NB / G)   // 64
#define PF  4            // prefetch depth (rows ahead, SGPR-resident)

typedef float f32x4 __attribute__((ext_vector_type(4)));  // native vec for nt-store

// counts int32 -> float mirror (lets main loop feed FMAs straight from SGPRs)
__global__ void fge_cvt(const int* __restrict__ counts, float* __restrict__ cf)
{
    int i = blockIdx.x * blockDim.x + threadIdx.x;       // int4 index
    const int n4 = NB * NG / 4;
    for (; i < n4; i += gridDim.x * blockDim.x) {
        int4 v = reinterpret_cast<const int4*>(counts)[i];
        f32x4 f = { (float)v.x, (float)v.y, (float)v.z, (float)v.w };
        __builtin_nontemporal_store(f, reinterpret_cast<f32x4*>(cf) + i);
    }
}

// M[g][o] = sum_s Wg[g][s] * Wagg[o][g*64+s];  Mb[g][o] = same with bg
__global__ void fge_pre1(const float* __restrict__ Wg,
                         const float* __restrict__ bg,
                         const float* __restrict__ Wagg,
                         float* __restrict__ M, float* __restrict__ Mb)
{
    int tid = blockIdx.x * blockDim.x + threadIdx.x;
    if (tid >= ED * NG) return;
    int o = tid / NG, g = tid % NG;   // 12 consecutive threads share one Wagg row
    const float* wrow = Wagg + (size_t)o * ED + g * SD;
    const float* wgp  = Wg + g * SD;
    const float* bgp  = bg + g * SD;
    float m = 0.f, mb = 0.f;
    #pragma unroll
    for (int s = 0; s < SD; ++s) {
        float w = wrow[s];
        m  += wgp[s] * w;
        mb += bgp[s] * w;
    }
    M [g * ED + o] = m;
    Mb[g * ED + o] = mb;
}

// c0[o] = bagg[o] + sum_g Mb[g][o]
__global__ void fge_pre2(const float* __restrict__ Mb,
                         const float* __restrict__ bagg,
                         float* __restrict__ c0)
{
    int o = blockIdx.x * blockDim.x + threadIdx.x;
    if (o >= ED) return;
    float s = bagg[o];
    #pragma unroll
    for (int g = 0; g < NG; ++g) s += Mb[g * ED + o];
    c0[o] = s;
}

__device__ __forceinline__ void row_fma_store_f(float4 ca, float4 cb, float4 cc,
                                                const float (&m)[NG][4],
                                                float4 base, float* __restrict__ dst)
{
    float cf[NG] = { ca.x, ca.y, ca.z, ca.w,
                     cb.x, cb.y, cb.z, cb.w,
                     cc.x, cc.y, cc.z, cc.w };   // SGPR-resident floats
    float4 acc = base;
    #pragma unroll
    for (int g = 0; g < NG; ++g) {               // v_fma: 1 SGPR operand, legal
        acc.x = fmaf(cf[g], m[g][0], acc.x);
        acc.y = fmaf(cf[g], m[g][1], acc.y);
        acc.z = fmaf(cf[g], m[g][2], acc.z);
        acc.w = fmaf(cf[g], m[g][3], acc.w);
    }
    f32x4 v = { acc.x, acc.y, acc.z, acc.w };
    __builtin_nontemporal_store(v, reinterpret_cast<f32x4*>(dst));  // r6: -25%
}

// Main (float-counts path): ~60 VGPR -> 8 waves/SIMD with 16B/lane nt stores.
__global__ __launch_bounds__(TPB, 8) void fge_main_f(const float* __restrict__ countsf,
                                                     const float* __restrict__ M,
                                                     const float* __restrict__ c0,
                                                     float* __restrict__ out)
{
    const int t  = threadIdx.x;
    const int o0 = t * 4;

    float m[NG][4];
    #pragma unroll
    for (int g = 0; g < NG; ++g) {
        float4 v = *reinterpret_cast<const float4*>(M + g * ED + o0);
        m[g][0] = v.x; m[g][1] = v.y; m[g][2] = v.z; m[g][3] = v.w;
    }
    const float4 base = *reinterpret_cast<const float4*>(c0 + o0);

    const float4* cp = reinterpret_cast<const float4*>(countsf);  // 3 per row

    float4 P[PF][3];   // uniform-address loads -> s_load_dwordx4, SGPR file
    #pragma unroll
    for (int k = 0; k < PF; ++k) {
        int r = blockIdx.x + k * G;
        P[k][0] = cp[r * 3]; P[k][1] = cp[r * 3 + 1]; P[k][2] = cp[r * 3 + 2];
    }

    int b = blockIdx.x;
    #pragma unroll 1
    for (int i = 0; i < ITERS; i += PF) {
        #pragma unroll
        for (int k = 0; k < PF; ++k) {
            row_fma_store_f(P[k][0], P[k][1], P[k][2], m, base,
                            out + (size_t)(b + k * G) * ED + o0);
            int pr = b + (k + PF) * G; pr = pr < NB ? pr : NB - 1;  // clamp tail
            P[k][0] = cp[pr * 3]; P[k][1] = cp[pr * 3 + 1]; P[k][2] = cp[pr * 3 + 2];
        }
        b += PF * G;
    }
}

// Fallback main (int counts, round-7 proven, 168 us)
__device__ __forceinline__ void row_compute_i(int4 x, int4 y, int4 z,
                                              const float (&m)[NG][4],
                                              float4 base, float* __restrict__ dst)
{
    float cf[NG] = { (float)x.x, (float)x.y, (float)x.z, (float)x.w,
                     (float)y.x, (float)y.y, (float)y.z, (float)y.w,
                     (float)z.x, (float)z.y, (float)z.z, (float)z.w };
    float4 acc = base;
    #pragma unroll
    for (int g = 0; g < NG; ++g) {
        acc.x = fmaf(cf[g], m[g][0], acc.x);
        acc.y = fmaf(cf[g], m[g][1], acc.y);
        acc.z = fmaf(cf[g], m[g][2], acc.z);
        acc.w = fmaf(cf[g], m[g][3], acc.w);
    }
    f32x4 v = { acc.x, acc.y, acc.z, acc.w };
    __builtin_nontemporal_store(v, reinterpret_cast<f32x4*>(dst));
}

__global__ __launch_bounds__(TPB) void fge_main_i(const int* __restrict__ counts,
                                                  const float* __restrict__ M,
                                                  const float* __restrict__ c0,
                                                  float* __restrict__ out)
{
    const int t  = threadIdx.x;
    const int o0 = t * 4;

    float m[NG][4];
    #pragma unroll
    for (int g = 0; g < NG; ++g) {
        float4 v = *reinterpret_cast<const float4*>(M + g * ED + o0);
        m[g][0] = v.x; m[g][1] = v.y; m[g][2] = v.z; m[g][3] = v.w;
    }
    const float4 base = *reinterpret_cast<const float4*>(c0 + o0);

    const int4* cp = reinterpret_cast<const int4*>(counts);
    int4 P[PF][3];
    #pragma unroll
    for (int k = 0; k < PF; ++k) {
        int r = blockIdx.x + k * G;
        P[k][0] = cp[r * 3]; P[k][1] = cp[r * 3 + 1]; P[k][2] = cp[r * 3 + 2];
    }

    int b = blockIdx.x;
    #pragma unroll 1
    for (int i = 0; i < ITERS; i += PF) {
        #pragma unroll
        for (int k = 0; k < PF; ++k) {
            row_compute_i(P[k][0], P[k][1], P[k][2], m, base,
                          out + (size_t)(b + k * G) * ED + o0);
            int pr = b + (k + PF) * G; pr = pr < NB ? pr : NB - 1;
            P[k][0] = cp[pr * 3]; P[k][1] = cp[pr * 3 + 1]; P[k][2] = cp[pr * 3 + 2];
        }
        b += PF * G;
    }
}

extern "C" void kernel_launch(void* const* d_in, const int* in_sizes, int n_in,
                              void* d_out, int out_size, void* d_ws, size_t ws_size,
                              hipStream_t stream) {
    const int*   counts = (const int*)  d_in[0];
    const float* Wg     = (const float*)d_in[1];
    const float* bg     = (const float*)d_in[2];
    const float* Wagg   = (const float*)d_in[3];
    const float* bagg   = (const float*)d_in[4];
    float* out = (float*)d_out;

    // ws layout: countsf (12.58 MB, 16B-aligned at 0) | M | Mb | c0
    float* countsf = (float*)d_ws;
    float* M  = countsf + (size_t)NB * NG;   // 36 KB
    float* Mb = M  + NG * ED;                // 36 KB
    float* c0 = Mb + NG * ED;                // 3 KB
    const size_t need = ((size_t)NB * NG + 2 * NG * ED + ED) * sizeof(float);

    if (ws_size >= need) {
        fge_cvt<<<2048, 256, 0, stream>>>(counts, countsf);
        fge_pre1<<<(ED * NG + 255) / 256, 256, 0, stream>>>(Wg, bg, Wagg, M, Mb);
        fge_pre2<<<(ED + 255) / 256, 256, 0, stream>>>(Mb, bagg, c0);
        fge_main_f<<<G, TPB, 0, stream>>>(countsf, M, c0, out);
    } else {
        float* M2  = (float*)d_ws;
        float* Mb2 = M2 + NG * ED;
        float* c02 = Mb2 + NG * ED;
        fge_pre1<<<(ED * NG + 255) / 256, 256, 0, stream>>>(Wg, bg, Wagg, M2, Mb2);
        fge_pre2<<<(ED + 255) / 256, 256, 0, stream>>>(Mb2, bagg, c02);
        fge_main_i<<<G, TPB, 0, stream>>>(counts, M2, c02, out);
    }
}

// Round 10
// 165.809 us; speedup vs baseline: 1.1153x; 1.1153x over previous
//
#include <hip/hip_runtime.h>

#define NG 12
#define SD 64
#define ED 768
#define NB 262144
#define TPB 192          // 3 waves; thread t owns output cols [4t, 4t+4)
#define G   4096         // grid size; ITERS grid-stride iterations per block
#define ITERS (NB / G)   // 64
#define PF  4            // prefetch depth (rows ahead, group-pipelined s_loads)

typedef float f32x2 __attribute__((ext_vector_type(2)));
typedef float f32x4 __attribute__((ext_vector_type(4)));

// Fused precompute: one kernel, 48 blocks of 192 threads = 16 o-values x 12 g.
// Thread (o,g): M[g][o] = sum_s Wg[g][s]*Wagg[o][g*64+s]; LDS-reduce the bg
// variant over g to produce c0[o] = bagg[o] + sum_{g,s} bg[g][s]*Wagg[o][...].
__global__ __launch_bounds__(192) void fge_pre(const float* __restrict__ Wg,
                                               const float* __restrict__ bg,
                                               const float* __restrict__ Wagg,
                                               const float* __restrict__ bagg,
                                               float* __restrict__ M,
                                               float* __restrict__ c0)
{
    __shared__ float smb[16][NG];
    const int t  = threadIdx.x;
    const int oi = t / NG;                 // 0..15 within block
    const int g  = t % NG;
    const int o  = blockIdx.x * 16 + oi;   // 48*16 = 768 exactly

    const float* wrow = Wagg + (size_t)o * ED + g * SD;
    const float* wgp  = Wg + g * SD;
    const float* bgp  = bg + g * SD;
    float m = 0.f, mb = 0.f;
    #pragma unroll
    for (int s = 0; s < SD; ++s) {
        float w = wrow[s];
        m  += wgp[s] * w;
        mb += bgp[s] * w;
    }
    M[g * ED + o] = m;
    smb[oi][g] = mb;
    __syncthreads();
    if (g == 0) {
        float s = bagg[o];
        #pragma unroll
        for (int gg = 0; gg < NG; ++gg) s += smb[oi][gg];
        c0[o] = s;
    }
}

__device__ __forceinline__ void row_compute(int4 x, int4 y, int4 z,
                                            const f32x2 (&m01)[NG],
                                            const f32x2 (&m23)[NG],
                                            f32x2 b01, f32x2 b23,
                                            float* __restrict__ dst)
{
    float cf[NG] = { (float)x.x, (float)x.y, (float)x.z, (float)x.w,
                     (float)y.x, (float)y.y, (float)y.z, (float)y.w,
                     (float)z.x, (float)z.y, (float)z.z, (float)z.w };
    f32x2 a01 = b01, a23 = b23;
    #pragma unroll
    for (int g = 0; g < NG; ++g) {
        f32x2 c2 = { cf[g], cf[g] };             // splat; backend uses op_sel
        a01 = __builtin_elementwise_fma(c2, m01[g], a01);  // v_pk_fma_f32
        a23 = __builtin_elementwise_fma(c2, m23[g], a23);
    }
    f32x4 v = { a01.x, a01.y, a23.x, a23.y };
    // nt store: LLC no-allocate, keeps L2 clean (round 6: -25%)
    __builtin_nontemporal_store(v, reinterpret_cast<f32x4*>(dst));
}

// out[b][o] = c0[o] + sum_g counts[b][g] * M[g][o]
// Grid-stride (compact moving write window) + PF-deep group-pipelined s_loads.
__global__ __launch_bounds__(TPB) void fge_main(const int* __restrict__ counts,
                                                const float* __restrict__ M,
                                                const float* __restrict__ c0,
                                                float* __restrict__ out)
{
    const int t  = threadIdx.x;
    const int o0 = t * 4;

    f32x2 m01[NG], m23[NG];
    #pragma unroll
    for (int g = 0; g < NG; ++g) {
        float4 v = *reinterpret_cast<const float4*>(M + g * ED + o0);
        m01[g] = (f32x2){ v.x, v.y };
        m23[g] = (f32x2){ v.z, v.w };
    }
    const float4 b4 = *reinterpret_cast<const float4*>(c0 + o0);
    const f32x2 b01 = { b4.x, b4.y }, b23 = { b4.z, b4.w };

    const int4* cp = reinterpret_cast<const int4*>(counts);  // 3 int4 per row

    int4 P[PF][3];   // uniform addr -> s_load_dwordx4 x3 per row
    #pragma unroll
    for (int k = 0; k < PF; ++k) {
        int r = blockIdx.x + k * G;
        P[k][0] = cp[r * 3]; P[k][1] = cp[r * 3 + 1]; P[k][2] = cp[r * 3 + 2];
    }

    int b = blockIdx.x;
    #pragma unroll 1
    for (int i = 0; i < ITERS; i += PF) {
        #pragma unroll
        for (int k = 0; k < PF; ++k) {
            row_compute(P[k][0], P[k][1], P[k][2], m01, m23, b01, b23,
                        out + (size_t)(b + k * G) * ED + o0);
            int pr = b + (k + PF) * G; pr = pr < NB ? pr : NB - 1;  // clamp tail
            P[k][0] = cp[pr * 3]; P[k][1] = cp[pr * 3 + 1]; P[k][2] = cp[pr * 3 + 2];
        }
        b += PF * G;
    }
}

extern "C" void kernel_launch(void* const* d_in, const int* in_sizes, int n_in,
                              void* d_out, int out_size, void* d_ws, size_t ws_size,
                              hipStream_t stream) {
    const int*   counts = (const int*)  d_in[0];
    const float* Wg     = (const float*)d_in[1];
    const float* bg     = (const float*)d_in[2];
    const float* Wagg   = (const float*)d_in[3];
    const float* bagg   = (const float*)d_in[4];
    float* out = (float*)d_out;

    float* M  = (float*)d_ws;            // 12*768 = 36 KB
    float* c0 = M + NG * ED;             // 3 KB

    fge_pre<<<ED / 16, 192, 0, stream>>>(Wg, bg, Wagg, bagg, M, c0);
    fge_main<<<G, TPB, 0, stream>>>(counts, M, c0, out);
}